// Round 13
// baseline (123.907 us; speedup 1.0000x reference)
//
#include <hip/hip_runtime.h>
#include <hip/hip_bf16.h>
#include <cstdint>
#include <cstddef>

// RGCN layer: out = (x@W0 + sum_r h_r@W[r]) / max(deg,1)
// Round-13: k_fine sorts by 11-bit (dst&255, type) key -> per-node edge runs
// are type-monotone -> k_agg uses ONE float2 accumulator + wave-uniform flush
// (no 8-way switch, 2 VGPR acc). gemm BM=128 + preprocessing from round 12.

#define NDIM 128
#define NREL 8
#define KR   1024        // 8*128 (hcat row)
#define KCAT 1152        // 9*128 (GEMM K)
#define COARSE 196       // dst>>8 buckets
#define EPB 4096         // edges per hist/cscatter block

typedef __attribute__((ext_vector_type(8))) short bf16x8;
typedef __attribute__((ext_vector_type(4))) float f32x4;
typedef unsigned int uint32;

__device__ __forceinline__ short f2bf(float f){
  __hip_bfloat16 h = __float2bfloat16(f);
  return *reinterpret_cast<short*>(&h);
}
__device__ __forceinline__ float bfl(uint32 v){ return __uint_as_float(v << 16); }
__device__ __forceinline__ float bfh(uint32 v){ return __uint_as_float(v & 0xFFFF0000u); }

__device__ __forceinline__ void gload_lds16(const void* g, void* l){
  __builtin_amdgcn_global_load_lds(
      (const __attribute__((address_space(1))) unsigned int*)g,
      (__attribute__((address_space(3))) unsigned int*)l, 16, 0, 0);
}

// ---------- K1: casts + zero coarse_cnt + detect ----------
__global__ void k_prep(const float* __restrict__ x, uint32* __restrict__ xb, int n4, int xblocks,
                       const float* __restrict__ W, const float* __restrict__ W0,
                       short* __restrict__ Wb, int wblocks,
                       const int* __restrict__ ei, int* flag, int* coarse_cnt){
  int b = blockIdx.x;
  if (b < xblocks){
    int i = b * 256 + threadIdx.x;
    if (i >= n4) return;
    float4 f = ((const float4*)x)[i];
    uint32 lo = ((uint32)(unsigned short)f2bf(f.x)) | (((uint32)(unsigned short)f2bf(f.y)) << 16);
    uint32 hi = ((uint32)(unsigned short)f2bf(f.z)) | (((uint32)(unsigned short)f2bf(f.w)) << 16);
    ((uint2*)xb)[i] = make_uint2(lo, hi);
  } else if (b < xblocks + wblocks){
    int i = (b - xblocks) * 256 + threadIdx.x;
    if (i >= NDIM * KCAT) return;
    int j  = i / KCAT;
    int t  = i - j * KCAT;
    int r  = t >> 7;
    int kd = t & 127;
    float v = (r < NREL) ? W[(((size_t)r * NDIM + kd) << 7) + j] : W0[((size_t)kd << 7) + j];
    Wb[i] = f2bf(v);
  } else {
    if (threadIdx.x < COARSE) coarse_cnt[threadIdx.x] = 0;
    if (threadIdx.x < 64){
      int v = ei[2 * threadIdx.x + 1];
      unsigned long long m = __ballot(v == 0);
      if (threadIdx.x == 0) flag[0] = (m == ~0ull) ? 1 : 0;
    }
  }
}

// ---------- K2: decode + pack + coarse LDS hist + block reservations ----------
// kv: src bits 0-15, type bits 16-18, dst&255 bits 19-26
__global__ __launch_bounds__(1024) void k_hist(
    const int* __restrict__ ei, const int* __restrict__ et, const int* __restrict__ flag,
    uint32* __restrict__ kv, unsigned char* __restrict__ ctmp,
    int* __restrict__ coarse_cnt, int* __restrict__ blockRes, int E){
  __shared__ int h[COARSE];
  const int b = blockIdx.x;
  for (int i = threadIdx.x; i < COARSE; i += 1024) h[i] = 0;
  __syncthreads();
  const int is64 = flag[0];
  const int e0 = b * EPB;
  for (int i = threadIdx.x; i < EPB; i += 1024){
    int e = e0 + i;
    if (e < E){
      int s, d, t;
      if (is64){ s = ei[2*e]; d = ei[2*(E + e)]; t = et[2*e]; }
      else     { s = ei[e];   d = ei[E + e];     t = et[e];   }
      int c = d >> 8;
      kv[e]   = (uint32)s | ((uint32)t << 16) | ((uint32)(d & 255) << 19);
      ctmp[e] = (unsigned char)c;
      atomicAdd(&h[c], 1);
    }
  }
  __syncthreads();
  for (int c = threadIdx.x; c < COARSE; c += 1024){
    int cnt = h[c];
    int res = 0;
    if (cnt > 0) res = atomicAdd(&coarse_cnt[c], cnt);
    blockRes[b * COARSE + c] = res;
  }
}

// ---------- K3: scan coarse counts -> base ----------
__global__ void k_base(const int* __restrict__ coarse_cnt, int* __restrict__ base){
  __shared__ int sm[256];
  int t = threadIdx.x;
  int v = (t < COARSE) ? coarse_cnt[t] : 0;
  sm[t] = v; __syncthreads();
  #pragma unroll
  for (int off = 1; off < 256; off <<= 1){
    int xv = 0; if (t >= off) xv = sm[t - off];
    __syncthreads(); sm[t] += xv; __syncthreads();
  }
  if (t <= COARSE) base[t] = sm[t] - v;
}

// ---------- K4: coarse scatter (LDS cursors) ----------
__global__ __launch_bounds__(1024) void k_cscatter(
    const uint32* __restrict__ kv, const unsigned char* __restrict__ ctmp,
    const int* __restrict__ base, const int* __restrict__ blockRes,
    uint32* __restrict__ ckv, int E){
  __shared__ int cur[COARSE];
  const int b = blockIdx.x;
  for (int c = threadIdx.x; c < COARSE; c += 1024)
    cur[c] = base[c] + blockRes[b * COARSE + c];
  __syncthreads();
  const int e0 = b * EPB;
  for (int i = threadIdx.x; i < EPB; i += 1024){
    int e = e0 + i;
    if (e < E){
      uint32 v = kv[e];
      int c = ctmp[e];
      int pos = atomicAdd(&cur[c], 1);
      ckv[pos] = v;
    }
  }
}

// ---------- K5: per-bucket fine sort by 11-bit (dst&255,type) -> rs, esort ----------
__global__ __launch_bounds__(1024) void k_fine(
    const uint32* __restrict__ ckv, const int* __restrict__ base,
    uint32* __restrict__ esort, int* __restrict__ rs, int N){
  __shared__ int h[2048];
  __shared__ int part[1024];
  __shared__ int cur[2048];
  const int c  = blockIdx.x;
  const int lo = base[c], hi = base[c + 1];
  const int t  = threadIdx.x;
  h[2*t] = 0; h[2*t + 1] = 0;
  __syncthreads();
  for (int i = lo + t; i < hi; i += 1024)
    atomicAdd(&h[(ckv[i] >> 16) & 0x7FF], 1);    // key = (dst&255)<<3 | type
  __syncthreads();
  int v0 = h[2*t], v1 = h[2*t + 1];
  int s = v0 + v1;
  part[t] = s; __syncthreads();
  for (int off = 1; off < 1024; off <<= 1){
    int xv = 0; if (t >= off) xv = part[t - off];
    __syncthreads(); part[t] += xv; __syncthreads();
  }
  int excl = part[t] - s;                         // exclusive prefix of bin 2t
  cur[2*t]     = lo + excl;
  cur[2*t + 1] = lo + excl + v0;
  if ((t & 3) == 0){                              // bin 2t has (bin&7)==0
    int idx = c * 256 + (t >> 2);                 // node8 = (2t)>>3
    if (idx <= N) rs[idx] = lo + excl;
  }
  __syncthreads();
  for (int i = lo + t; i < hi; i += 1024){
    uint32 v2 = ckv[i];
    int pos = atomicAdd(&cur[(v2 >> 16) & 0x7FF], 1);
    esort[pos] = v2;
  }
}

// ---------- K6: aggregation: type-monotone runs, single accumulator ----------
__global__ __launch_bounds__(256) void k_agg(const uint32* __restrict__ xb,
                                             const int* __restrict__ rs,
                                             const uint32* __restrict__ esort,
                                             uint32* __restrict__ hcat,
                                             float* __restrict__ invdeg, int N){
  int wave = threadIdx.x >> 6;
  int lane = threadIdx.x & 63;
  int n = blockIdx.x * 4 + wave;
  if (n >= N) return;
  int beg = rs[n], end = rs[n + 1];
  size_t b2 = (size_t)n * (KR / 2);

  float ax = 0.f, ay = 0.f;
  int cur_r = 0;

  auto FLUSH = [&](int upto){   // store slot cur_r, zero (cur_r, upto), advance
    __hip_bfloat162 pk = __float22bfloat162_rn(make_float2(ax, ay));
    __builtin_nontemporal_store(*reinterpret_cast<uint32*>(&pk),
                                &hcat[b2 + cur_r * 64 + lane]);
    for (int r = cur_r + 1; r < upto; ++r)
      __builtin_nontemporal_store(0u, &hcat[b2 + r * 64 + lane]);
    ax = 0.f; ay = 0.f;
    cur_r = upto;
  };

  #define PROC(P, V) { int tt = (int)(((P) >> 16) & 7); \
                       if (tt != cur_r) FLUSH(tt); \
                       ax += bfl(V); ay += bfh(V); }

  int i = beg;
  for (; i + 7 < end; i += 8){
    uint32 p0 = __builtin_nontemporal_load(&esort[i]);
    uint32 p1 = __builtin_nontemporal_load(&esort[i+1]);
    uint32 p2 = __builtin_nontemporal_load(&esort[i+2]);
    uint32 p3 = __builtin_nontemporal_load(&esort[i+3]);
    uint32 p4 = __builtin_nontemporal_load(&esort[i+4]);
    uint32 p5 = __builtin_nontemporal_load(&esort[i+5]);
    uint32 p6 = __builtin_nontemporal_load(&esort[i+6]);
    uint32 p7 = __builtin_nontemporal_load(&esort[i+7]);
    uint32 v0 = xb[(size_t)(p0 & 0xFFFF) * 64 + lane];
    uint32 v1 = xb[(size_t)(p1 & 0xFFFF) * 64 + lane];
    uint32 v2 = xb[(size_t)(p2 & 0xFFFF) * 64 + lane];
    uint32 v3 = xb[(size_t)(p3 & 0xFFFF) * 64 + lane];
    uint32 v4 = xb[(size_t)(p4 & 0xFFFF) * 64 + lane];
    uint32 v5 = xb[(size_t)(p5 & 0xFFFF) * 64 + lane];
    uint32 v6 = xb[(size_t)(p6 & 0xFFFF) * 64 + lane];
    uint32 v7 = xb[(size_t)(p7 & 0xFFFF) * 64 + lane];
    PROC(p0, v0) PROC(p1, v1) PROC(p2, v2) PROC(p3, v3)
    PROC(p4, v4) PROC(p5, v5) PROC(p6, v6) PROC(p7, v7)
  }
  for (; i + 3 < end; i += 4){
    uint32 p0 = __builtin_nontemporal_load(&esort[i]);
    uint32 p1 = __builtin_nontemporal_load(&esort[i+1]);
    uint32 p2 = __builtin_nontemporal_load(&esort[i+2]);
    uint32 p3 = __builtin_nontemporal_load(&esort[i+3]);
    uint32 v0 = xb[(size_t)(p0 & 0xFFFF) * 64 + lane];
    uint32 v1 = xb[(size_t)(p1 & 0xFFFF) * 64 + lane];
    uint32 v2 = xb[(size_t)(p2 & 0xFFFF) * 64 + lane];
    uint32 v3 = xb[(size_t)(p3 & 0xFFFF) * 64 + lane];
    PROC(p0, v0) PROC(p1, v1) PROC(p2, v2) PROC(p3, v3)
  }
  for (; i < end; ++i){
    uint32 p = __builtin_nontemporal_load(&esort[i]);
    uint32 v = xb[(size_t)(p & 0xFFFF) * 64 + lane];
    PROC(p, v)
  }
  FLUSH(NREL);   // final slot + trailing zeros (handles empty nodes too)
  #undef PROC

  if (lane == 0){
    int d = end - beg;
    invdeg[n] = 1.0f / (float)(d > 0 ? d : 1);
  }
}

// ---------- K7: GEMM BM=128, 512 thr, 8 waves; A ks 16-17 from xb ----------
__global__ __launch_bounds__(512) void k_gemm2(
    const short* __restrict__ acat,   // [Npad][1024] bf16 (8 rel slots)
    const short* __restrict__ xbs,    // [Npad][128]  bf16 (self rows)
    const short* __restrict__ wb,     // [128][1152]  bf16
    const float* __restrict__ invdeg,
    float* __restrict__ out, int N)
{
  __shared__ char smem[65536];
  char* As0 = smem;
  char* As1 = smem + 16384;
  char* Bs0 = smem + 32768;
  char* Bs1 = smem + 49152;

  const int tid  = threadIdx.x;
  const int lane = tid & 63;
  const int wid  = tid >> 6;
  const int wr   = wid >> 1;
  const int wc   = wid & 1;
  const int n0   = blockIdx.x * 128;
  const int lr   = lane & 15;
  const int lq   = lane >> 4;

  f32x4 acc[2][4];
  #pragma unroll
  for (int m = 0; m < 2; ++m)
    #pragma unroll
    for (int p = 0; p < 4; ++p)
      acc[m][p] = (f32x4){0.f, 0.f, 0.f, 0.f};

  const int srow = tid >> 3;
  const int scs  = tid & 7;

  auto STAGE = [&](char* Ab, char* Bb, int ks){
    const short* ab;
    size_t rstride;
    if (ks < 16){ ab = acat + (size_t)n0 * KR + ks * 64;          rstride = KR;  }
    else        { ab = xbs  + (size_t)n0 * 128 + (ks - 16) * 64;  rstride = 128; }
    #pragma unroll
    for (int q = 0; q < 2; ++q){
      int row = q * 64 + srow;
      const short* src = ab + (size_t)row * rstride + ((scs ^ (row & 7)) << 3);
      gload_lds16(src, Ab + q * 8192 + (wid << 10));
    }
    const short* bb = wb + ks * 64;
    #pragma unroll
    for (int q = 0; q < 2; ++q){
      int j = q * 64 + srow;
      const short* src = bb + (size_t)j * KCAT + ((scs ^ (j & 7)) << 3);
      gload_lds16(src, Bb + q * 8192 + (wid << 10));
    }
  };

  auto COMPUTE = [&](const char* Ab, const char* Bb){
    bf16x8 a[2][2], b[2][4];
    #pragma unroll
    for (int kk = 0; kk < 2; ++kk){
      #pragma unroll
      for (int m = 0; m < 2; ++m){
        int row = wr * 32 + m * 16 + lr;
        int c   = kk * 4 + lq;
        a[kk][m] = *(const bf16x8*)(Ab + row * 128 + ((c ^ (row & 7)) << 4));
      }
      #pragma unroll
      for (int p = 0; p < 4; ++p){
        int j = wc * 64 + p * 16 + lr;
        int c = kk * 4 + lq;
        b[kk][p] = *(const bf16x8*)(Bb + j * 128 + ((c ^ (j & 7)) << 4));
      }
    }
    #pragma unroll
    for (int kk = 0; kk < 2; ++kk)
      #pragma unroll
      for (int m = 0; m < 2; ++m)
        #pragma unroll
        for (int p = 0; p < 4; ++p)
          acc[m][p] = __builtin_amdgcn_mfma_f32_16x16x32_bf16(a[kk][m], b[kk][p], acc[m][p], 0, 0, 0);
  };

  STAGE(As0, Bs0, 0);
  __syncthreads();
  for (int ks = 0; ks < 18; ks += 2){
    STAGE(As1, Bs1, ks + 1);
    COMPUTE(As0, Bs0);
    __syncthreads();
    if (ks + 2 < 18) STAGE(As0, Bs0, ks + 2);
    COMPUTE(As1, Bs1);
    __syncthreads();
  }

  #pragma unroll
  for (int m = 0; m < 2; ++m){
    int rbase = n0 + wr * 32 + m * 16 + lq * 4;
    #pragma unroll
    for (int v = 0; v < 4; ++v){
      int ro = rbase + v;
      if (ro < N){
        float inv = invdeg[ro];
        #pragma unroll
        for (int p = 0; p < 4; ++p)
          __builtin_nontemporal_store(acc[m][p][v] * inv,
              &out[(((size_t)ro) << 7) + wc * 64 + p * 16 + lr]);
      }
    }
  }
}

extern "C" void kernel_launch(void* const* d_in, const int* in_sizes, int n_in,
                              void* d_out, int out_size, void* d_ws, size_t ws_size,
                              hipStream_t stream){
  const float* x  = (const float*)d_in[0];
  const int*   ei = (const int*)d_in[1];
  const int*   et = (const int*)d_in[2];
  const float* W  = (const float*)d_in[4];
  const float* W0 = (const float*)d_in[5];
  float* out = (float*)d_out;

  const int N = in_sizes[0] / NDIM;   // 50000
  const int E = in_sizes[2];          // 800000
  const int Npad = N + 128;
  const int nblkE = (E + EPB - 1) / EPB;   // 196

  char* ws = (char*)d_ws;
  size_t off = 0;
  auto alloc = [&](size_t bytes)->size_t{
    size_t p = off; off = (off + bytes + 255) & ~(size_t)255; return p;
  };
  size_t o_flag = alloc(4);
  size_t o_kv   = alloc((size_t)E * 4);
  size_t o_ct   = alloc((size_t)E);
  size_t o_ckv  = alloc((size_t)E * 4);
  size_t o_es   = alloc((size_t)E * 4);
  size_t o_cc   = alloc(COARSE * 4);
  size_t o_base = alloc((COARSE + 2) * 4);
  size_t o_br   = alloc((size_t)nblkE * COARSE * 4);
  size_t o_rs   = alloc((size_t)(N + 1) * 4);
  size_t o_inv  = alloc((size_t)N * 4);
  size_t o_h    = alloc((size_t)Npad * KR * 2);
  size_t o_wb   = alloc((size_t)NDIM * KCAT * 2);
  size_t o_xb   = alloc((size_t)Npad * NDIM * 2);
  (void)ws_size;

  int*  flag   = (int*)(ws + o_flag);
  uint32* kv   = (uint32*)(ws + o_kv);
  unsigned char* ctmp = (unsigned char*)(ws + o_ct);
  uint32* ckv  = (uint32*)(ws + o_ckv);
  uint32* esort= (uint32*)(ws + o_es);
  int*  ccnt   = (int*)(ws + o_cc);
  int*  base   = (int*)(ws + o_base);
  int*  bres   = (int*)(ws + o_br);
  int*  rs     = (int*)(ws + o_rs);
  float* invdeg= (float*)(ws + o_inv);
  uint32* hcat = (uint32*)(ws + o_h);
  short* acat  = (short*)(ws + o_h);
  short* Wbs   = (short*)(ws + o_wb);
  uint32* xb   = (uint32*)(ws + o_xb);
  short* xbs   = (short*)(ws + o_xb);

  const int n4      = N * NDIM / 4;
  const int xblocks = (n4 + 255) / 256;             // 6250
  const int wblocks = (NDIM * KCAT + 255) / 256;    // 576

  k_prep<<<xblocks + wblocks + 1, 256, 0, stream>>>(
      x, xb, n4, xblocks, W, W0, Wbs, wblocks, ei, flag, ccnt);
  k_hist<<<nblkE, 1024, 0, stream>>>(ei, et, flag, kv, ctmp, ccnt, bres, E);
  k_base<<<1, 256, 0, stream>>>(ccnt, base);
  k_cscatter<<<nblkE, 1024, 0, stream>>>(kv, ctmp, base, bres, ckv, E);
  k_fine<<<COARSE, 1024, 0, stream>>>(ckv, base, esort, rs, N);
  k_agg<<<(N + 3) / 4, 256, 0, stream>>>(xb, rs, esort, hcat, invdeg, N);
  k_gemm2<<<(N + 127) / 128, 512, 0, stream>>>(acat, xbs, Wbs, invdeg, out, N);
}

// Round 14
// 105.159 us; speedup vs baseline: 1.1783x; 1.1783x over previous
//
#include <hip/hip_runtime.h>
#include <hip/hip_bf16.h>
#include <cstdint>
#include <cstddef>

// RGCN layer: out = (x@W0 + sum_r h_r@W[r]) / max(deg,1)
// Round-14 = round-12 exact revert (best known: 105.4 us).
//   k_prep: x->bf16, W->Wb^T bf16, zero coarse_cnt, int64 detect
//   k_hist/k_base/k_cscatter/k_fine: atomic-free (dst) edge grouping
//   k_agg: 1 wave/node, 8-way switch acc, 8-deep gather unroll, nt stores
//   k_gemm2: BM=128, 512 thr, 64KB LDS, gl_lds dbuf, A ks16-17 from xb

#define NDIM 128
#define NREL 8
#define KR   1024        // 8*128 (hcat row)
#define KCAT 1152        // 9*128 (GEMM K)
#define COARSE 196       // dst>>8 buckets
#define EPB 4096         // edges per hist/cscatter block

typedef __attribute__((ext_vector_type(8))) short bf16x8;
typedef __attribute__((ext_vector_type(4))) float f32x4;
typedef unsigned int uint32;

__device__ __forceinline__ short f2bf(float f){
  __hip_bfloat16 h = __float2bfloat16(f);
  return *reinterpret_cast<short*>(&h);
}
__device__ __forceinline__ float bfl(uint32 v){ return __uint_as_float(v << 16); }
__device__ __forceinline__ float bfh(uint32 v){ return __uint_as_float(v & 0xFFFF0000u); }

__device__ __forceinline__ void gload_lds16(const void* g, void* l){
  __builtin_amdgcn_global_load_lds(
      (const __attribute__((address_space(1))) unsigned int*)g,
      (__attribute__((address_space(3))) unsigned int*)l, 16, 0, 0);
}

// ---------- K1: casts + zero coarse_cnt + detect ----------
__global__ void k_prep(const float* __restrict__ x, uint32* __restrict__ xb, int n4, int xblocks,
                       const float* __restrict__ W, const float* __restrict__ W0,
                       short* __restrict__ Wb, int wblocks,
                       const int* __restrict__ ei, int* flag, int* coarse_cnt){
  int b = blockIdx.x;
  if (b < xblocks){
    int i = b * 256 + threadIdx.x;
    if (i >= n4) return;
    float4 f = ((const float4*)x)[i];
    uint32 lo = ((uint32)(unsigned short)f2bf(f.x)) | (((uint32)(unsigned short)f2bf(f.y)) << 16);
    uint32 hi = ((uint32)(unsigned short)f2bf(f.z)) | (((uint32)(unsigned short)f2bf(f.w)) << 16);
    ((uint2*)xb)[i] = make_uint2(lo, hi);
  } else if (b < xblocks + wblocks){
    int i = (b - xblocks) * 256 + threadIdx.x;
    if (i >= NDIM * KCAT) return;
    int j  = i / KCAT;
    int t  = i - j * KCAT;
    int r  = t >> 7;
    int kd = t & 127;
    float v = (r < NREL) ? W[(((size_t)r * NDIM + kd) << 7) + j] : W0[((size_t)kd << 7) + j];
    Wb[i] = f2bf(v);
  } else {
    if (threadIdx.x < COARSE) coarse_cnt[threadIdx.x] = 0;
    if (threadIdx.x < 64){
      int v = ei[2 * threadIdx.x + 1];
      unsigned long long m = __ballot(v == 0);
      if (threadIdx.x == 0) flag[0] = (m == ~0ull) ? 1 : 0;
    }
  }
}

// ---------- K2: decode + pack + coarse LDS hist + block reservations ----------
__global__ __launch_bounds__(1024) void k_hist(
    const int* __restrict__ ei, const int* __restrict__ et, const int* __restrict__ flag,
    uint32* __restrict__ kv, unsigned char* __restrict__ ctmp,
    int* __restrict__ coarse_cnt, int* __restrict__ blockRes, int E){
  __shared__ int h[COARSE];
  const int b = blockIdx.x;
  for (int i = threadIdx.x; i < COARSE; i += 1024) h[i] = 0;
  __syncthreads();
  const int is64 = flag[0];
  const int e0 = b * EPB;
  for (int i = threadIdx.x; i < EPB; i += 1024){
    int e = e0 + i;
    if (e < E){
      int s, d, t;
      if (is64){ s = ei[2*e]; d = ei[2*(E + e)]; t = et[2*e]; }
      else     { s = ei[e];   d = ei[E + e];     t = et[e];   }
      int c = d >> 8;
      kv[e]   = (uint32)s | ((uint32)t << 16) | ((uint32)(d & 255) << 19);
      ctmp[e] = (unsigned char)c;
      atomicAdd(&h[c], 1);
    }
  }
  __syncthreads();
  for (int c = threadIdx.x; c < COARSE; c += 1024){
    int cnt = h[c];
    int res = 0;
    if (cnt > 0) res = atomicAdd(&coarse_cnt[c], cnt);
    blockRes[b * COARSE + c] = res;
  }
}

// ---------- K3: scan coarse counts -> base ----------
__global__ void k_base(const int* __restrict__ coarse_cnt, int* __restrict__ base){
  __shared__ int sm[256];
  int t = threadIdx.x;
  int v = (t < COARSE) ? coarse_cnt[t] : 0;
  sm[t] = v; __syncthreads();
  #pragma unroll
  for (int off = 1; off < 256; off <<= 1){
    int xv = 0; if (t >= off) xv = sm[t - off];
    __syncthreads(); sm[t] += xv; __syncthreads();
  }
  if (t <= COARSE) base[t] = sm[t] - v;
}

// ---------- K4: coarse scatter (LDS cursors) ----------
__global__ __launch_bounds__(1024) void k_cscatter(
    const uint32* __restrict__ kv, const unsigned char* __restrict__ ctmp,
    const int* __restrict__ base, const int* __restrict__ blockRes,
    uint32* __restrict__ ckv, int E){
  __shared__ int cur[COARSE];
  const int b = blockIdx.x;
  for (int c = threadIdx.x; c < COARSE; c += 1024)
    cur[c] = base[c] + blockRes[b * COARSE + c];
  __syncthreads();
  const int e0 = b * EPB;
  for (int i = threadIdx.x; i < EPB; i += 1024){
    int e = e0 + i;
    if (e < E){
      uint32 v = kv[e];
      int c = ctmp[e];
      int pos = atomicAdd(&cur[c], 1);
      ckv[pos] = v;
    }
  }
}

// ---------- K5: per-bucket fine grouping by dst&255 -> rs[], esort ----------
__global__ __launch_bounds__(1024) void k_fine(
    const uint32* __restrict__ ckv, const int* __restrict__ base,
    uint32* __restrict__ esort, int* __restrict__ rs, int N){
  __shared__ int h[256];
  __shared__ int cur[256];
  const int c  = blockIdx.x;
  const int lo = base[c], hi = base[c + 1];
  const int t  = threadIdx.x;
  if (t < 256) h[t] = 0;
  __syncthreads();
  for (int i = lo + t; i < hi; i += 1024)
    atomicAdd(&h[(ckv[i] >> 19) & 255], 1);
  __syncthreads();
  int v = (t < 256) ? h[t] : 0;
  __syncthreads();
  for (int off = 1; off < 256; off <<= 1){
    int xv = 0;
    if (t < 256 && t >= off) xv = h[t - off];
    __syncthreads();
    if (t < 256) h[t] += xv;
    __syncthreads();
  }
  if (t < 256){
    int excl = h[t] - v;
    cur[t] = lo + excl;
    int idx = c * 256 + t;
    if (idx <= N) rs[idx] = lo + excl;
  }
  __syncthreads();
  for (int i = lo + t; i < hi; i += 1024){
    uint32 v2 = ckv[i];
    int pos = atomicAdd(&cur[(v2 >> 19) & 255], 1);
    esort[pos] = v2;
  }
}

// ---------- K6: aggregation: 8-deep unroll, nt stores, 8-slot rows ----------
#define ACCUM(P, V) \
  switch (((P) >> 16) & 7){ \
    case 0: acc[0].x+=bfl(V); acc[0].y+=bfh(V); break; case 1: acc[1].x+=bfl(V); acc[1].y+=bfh(V); break; \
    case 2: acc[2].x+=bfl(V); acc[2].y+=bfh(V); break; case 3: acc[3].x+=bfl(V); acc[3].y+=bfh(V); break; \
    case 4: acc[4].x+=bfl(V); acc[4].y+=bfh(V); break; case 5: acc[5].x+=bfl(V); acc[5].y+=bfh(V); break; \
    case 6: acc[6].x+=bfl(V); acc[6].y+=bfh(V); break; case 7: acc[7].x+=bfl(V); acc[7].y+=bfh(V); break; \
  }

__global__ __launch_bounds__(256) void k_agg(const uint32* __restrict__ xb,
                                             const int* __restrict__ rs,
                                             const uint32* __restrict__ esort,
                                             uint32* __restrict__ hcat,
                                             float* __restrict__ invdeg, int N){
  int wave = threadIdx.x >> 6;
  int lane = threadIdx.x & 63;
  int n = blockIdx.x * 4 + wave;
  if (n >= N) return;
  int beg = rs[n], end = rs[n + 1];
  float2 acc[NREL];
  #pragma unroll
  for (int r = 0; r < NREL; ++r){ acc[r].x = 0.f; acc[r].y = 0.f; }

  int i = beg;
  for (; i + 7 < end; i += 8){
    uint32 p0 = esort[i],   p1 = esort[i+1], p2 = esort[i+2], p3 = esort[i+3];
    uint32 p4 = esort[i+4], p5 = esort[i+5], p6 = esort[i+6], p7 = esort[i+7];
    uint32 v0 = xb[(size_t)(p0 & 0xFFFF) * 64 + lane];
    uint32 v1 = xb[(size_t)(p1 & 0xFFFF) * 64 + lane];
    uint32 v2 = xb[(size_t)(p2 & 0xFFFF) * 64 + lane];
    uint32 v3 = xb[(size_t)(p3 & 0xFFFF) * 64 + lane];
    uint32 v4 = xb[(size_t)(p4 & 0xFFFF) * 64 + lane];
    uint32 v5 = xb[(size_t)(p5 & 0xFFFF) * 64 + lane];
    uint32 v6 = xb[(size_t)(p6 & 0xFFFF) * 64 + lane];
    uint32 v7 = xb[(size_t)(p7 & 0xFFFF) * 64 + lane];
    ACCUM(p0, v0) ACCUM(p1, v1) ACCUM(p2, v2) ACCUM(p3, v3)
    ACCUM(p4, v4) ACCUM(p5, v5) ACCUM(p6, v6) ACCUM(p7, v7)
  }
  for (; i + 3 < end; i += 4){
    uint32 p0 = esort[i], p1 = esort[i+1], p2 = esort[i+2], p3 = esort[i+3];
    uint32 v0 = xb[(size_t)(p0 & 0xFFFF) * 64 + lane];
    uint32 v1 = xb[(size_t)(p1 & 0xFFFF) * 64 + lane];
    uint32 v2 = xb[(size_t)(p2 & 0xFFFF) * 64 + lane];
    uint32 v3 = xb[(size_t)(p3 & 0xFFFF) * 64 + lane];
    ACCUM(p0, v0) ACCUM(p1, v1) ACCUM(p2, v2) ACCUM(p3, v3)
  }
  for (; i < end; ++i){
    uint32 p = esort[i];
    uint32 v = xb[(size_t)(p & 0xFFFF) * 64 + lane];
    ACCUM(p, v)
  }

  size_t b2 = (size_t)n * (KR / 2);
  #pragma unroll
  for (int r = 0; r < NREL; ++r){
    __hip_bfloat162 pk = __float22bfloat162_rn(make_float2(acc[r].x, acc[r].y));
    __builtin_nontemporal_store(*reinterpret_cast<uint32*>(&pk), &hcat[b2 + r * 64 + lane]);
  }
  if (lane == 0){
    int d = end - beg;
    invdeg[n] = 1.0f / (float)(d > 0 ? d : 1);
  }
}

// ---------- K7: GEMM BM=128, 512 thr, 8 waves; A ks 16-17 from xb ----------
__global__ __launch_bounds__(512) void k_gemm2(
    const short* __restrict__ acat,   // [Npad][1024] bf16 (8 rel slots)
    const short* __restrict__ xbs,    // [Npad][128]  bf16 (self rows)
    const short* __restrict__ wb,     // [128][1152]  bf16
    const float* __restrict__ invdeg,
    float* __restrict__ out, int N)
{
  __shared__ char smem[65536];        // As0 16K | As1 16K | Bs0 16K | Bs1 16K
  char* As0 = smem;
  char* As1 = smem + 16384;
  char* Bs0 = smem + 32768;
  char* Bs1 = smem + 49152;

  const int tid  = threadIdx.x;
  const int lane = tid & 63;
  const int wid  = tid >> 6;          // 0..7
  const int wr   = wid >> 1;          // 0..3 : 32-row group
  const int wc   = wid & 1;           // 0..1 : 64-col group
  const int n0   = blockIdx.x * 128;
  const int lr   = lane & 15;
  const int lq   = lane >> 4;

  f32x4 acc[2][4];
  #pragma unroll
  for (int m = 0; m < 2; ++m)
    #pragma unroll
    for (int p = 0; p < 4; ++p)
      acc[m][p] = (f32x4){0.f, 0.f, 0.f, 0.f};

  const int srow = tid >> 3;   // 0..63
  const int scs  = tid & 7;

  auto STAGE = [&](char* Ab, char* Bb, int ks){
    const short* ab;
    size_t rstride;
    if (ks < 16){ ab = acat + (size_t)n0 * KR + ks * 64;          rstride = KR;  }
    else        { ab = xbs  + (size_t)n0 * 128 + (ks - 16) * 64;  rstride = 128; }
    #pragma unroll
    for (int q = 0; q < 2; ++q){
      int row = q * 64 + srow;
      const short* src = ab + (size_t)row * rstride + ((scs ^ (row & 7)) << 3);
      gload_lds16(src, Ab + q * 8192 + (wid << 10));
    }
    const short* bb = wb + ks * 64;
    #pragma unroll
    for (int q = 0; q < 2; ++q){
      int j = q * 64 + srow;
      const short* src = bb + (size_t)j * KCAT + ((scs ^ (j & 7)) << 3);
      gload_lds16(src, Bb + q * 8192 + (wid << 10));
    }
  };

  auto COMPUTE = [&](const char* Ab, const char* Bb){
    bf16x8 a[2][2], b[2][4];
    #pragma unroll
    for (int kk = 0; kk < 2; ++kk){
      #pragma unroll
      for (int m = 0; m < 2; ++m){
        int row = wr * 32 + m * 16 + lr;
        int c   = kk * 4 + lq;
        a[kk][m] = *(const bf16x8*)(Ab + row * 128 + ((c ^ (row & 7)) << 4));
      }
      #pragma unroll
      for (int p = 0; p < 4; ++p){
        int j = wc * 64 + p * 16 + lr;
        int c = kk * 4 + lq;
        b[kk][p] = *(const bf16x8*)(Bb + j * 128 + ((c ^ (j & 7)) << 4));
      }
    }
    #pragma unroll
    for (int kk = 0; kk < 2; ++kk)
      #pragma unroll
      for (int m = 0; m < 2; ++m)
        #pragma unroll
        for (int p = 0; p < 4; ++p)
          acc[m][p] = __builtin_amdgcn_mfma_f32_16x16x32_bf16(a[kk][m], b[kk][p], acc[m][p], 0, 0, 0);
  };

  STAGE(As0, Bs0, 0);
  __syncthreads();
  for (int ks = 0; ks < 18; ks += 2){
    STAGE(As1, Bs1, ks + 1);
    COMPUTE(As0, Bs0);
    __syncthreads();
    if (ks + 2 < 18) STAGE(As0, Bs0, ks + 2);
    COMPUTE(As1, Bs1);
    __syncthreads();
  }

  #pragma unroll
  for (int m = 0; m < 2; ++m){
    int rbase = n0 + wr * 32 + m * 16 + lq * 4;
    #pragma unroll
    for (int v = 0; v < 4; ++v){
      int ro = rbase + v;
      if (ro < N){
        float inv = invdeg[ro];
        #pragma unroll
        for (int p = 0; p < 4; ++p)
          __builtin_nontemporal_store(acc[m][p][v] * inv,
              &out[(((size_t)ro) << 7) + wc * 64 + p * 16 + lr]);
      }
    }
  }
}

extern "C" void kernel_launch(void* const* d_in, const int* in_sizes, int n_in,
                              void* d_out, int out_size, void* d_ws, size_t ws_size,
                              hipStream_t stream){
  const float* x  = (const float*)d_in[0];
  const int*   ei = (const int*)d_in[1];
  const int*   et = (const int*)d_in[2];
  const float* W  = (const float*)d_in[4];
  const float* W0 = (const float*)d_in[5];
  float* out = (float*)d_out;

  const int N = in_sizes[0] / NDIM;   // 50000
  const int E = in_sizes[2];          // 800000
  const int Npad = N + 128;           // BM=128 tail tile stays in-bounds
  const int nblkE = (E + EPB - 1) / EPB;   // 196

  char* ws = (char*)d_ws;
  size_t off = 0;
  auto alloc = [&](size_t bytes)->size_t{
    size_t p = off; off = (off + bytes + 255) & ~(size_t)255; return p;
  };
  size_t o_flag = alloc(4);
  size_t o_kv   = alloc((size_t)E * 4);
  size_t o_ct   = alloc((size_t)E);
  size_t o_ckv  = alloc((size_t)E * 4);
  size_t o_es   = alloc((size_t)E * 4);
  size_t o_cc   = alloc(COARSE * 4);
  size_t o_base = alloc((COARSE + 2) * 4);
  size_t o_br   = alloc((size_t)nblkE * COARSE * 4);
  size_t o_rs   = alloc((size_t)(N + 1) * 4);
  size_t o_inv  = alloc((size_t)N * 4);
  size_t o_h    = alloc((size_t)Npad * KR * 2);
  size_t o_wb   = alloc((size_t)NDIM * KCAT * 2);
  size_t o_xb   = alloc((size_t)Npad * NDIM * 2);   // padded for GEMM tail
  (void)ws_size;

  int*  flag   = (int*)(ws + o_flag);
  uint32* kv   = (uint32*)(ws + o_kv);
  unsigned char* ctmp = (unsigned char*)(ws + o_ct);
  uint32* ckv  = (uint32*)(ws + o_ckv);
  uint32* esort= (uint32*)(ws + o_es);
  int*  ccnt   = (int*)(ws + o_cc);
  int*  base   = (int*)(ws + o_base);
  int*  bres   = (int*)(ws + o_br);
  int*  rs     = (int*)(ws + o_rs);
  float* invdeg= (float*)(ws + o_inv);
  uint32* hcat = (uint32*)(ws + o_h);
  short* acat  = (short*)(ws + o_h);
  short* Wbs   = (short*)(ws + o_wb);
  uint32* xb   = (uint32*)(ws + o_xb);
  short* xbs   = (short*)(ws + o_xb);

  const int n4      = N * NDIM / 4;
  const int xblocks = (n4 + 255) / 256;             // 6250
  const int wblocks = (NDIM * KCAT + 255) / 256;    // 576

  k_prep<<<xblocks + wblocks + 1, 256, 0, stream>>>(
      x, xb, n4, xblocks, W, W0, Wbs, wblocks, ei, flag, ccnt);
  k_hist<<<nblkE, 1024, 0, stream>>>(ei, et, flag, kv, ctmp, ccnt, bres, E);
  k_base<<<1, 256, 0, stream>>>(ccnt, base);
  k_cscatter<<<nblkE, 1024, 0, stream>>>(kv, ctmp, base, bres, ckv, E);
  k_fine<<<COARSE, 1024, 0, stream>>>(ckv, base, esort, rs, N);
  k_agg<<<(N + 3) / 4, 256, 0, stream>>>(xb, rs, esort, hcat, invdeg, N);
  k_gemm2<<<(N + 127) / 128, 512, 0, stream>>>(acat, xbs, Wbs, invdeg, out, N);
}